// Round 11
// baseline (103.582 us; speedup 1.0000x reference)
//
#include <hip/hip_runtime.h>

#define N_NODES 40000
#define N_EDGES 640000
#define D 128
#define KCAT 256    // concat-K: [x | agg]
#define CAP 64      // bucket capacity; P(deg>=64 | Binom(640K,1/40K)) ~ 4e-13 total
#define NXCD 8
#define PART 5000   // nodes per XCD partition
#define PLCAP 84000 // per-partition compacted-list capacity (mean 80K, +15 sigma)
#define CCAP 224    // per-block per-partition compact capacity (mean 128, +9 sigma)

typedef __attribute__((ext_vector_type(8))) short short8v;
typedef __attribute__((ext_vector_type(4))) float f32x4;
typedef __attribute__((ext_vector_type(2))) float f32x2;

// ---------------------------------------------------------------------------
// Pipeline (4 dispatches):
//   memset(deg+pcur) -> prep (convert+Wcat+compact) -> bucket -> fused gemm
//
// Workspace:
//   Wcat  : 128*256 bf16 (64 KB)    B^T layout: Wcat[j][k], k<128->Ws else Wn
//   deg   : N_NODES ints            atomic cursors (zeroed by memset)
//   pcur  : NXCD ints               per-partition list cursors (zeroed)
//   slot  : N_NODES*CAP ushorts     (5.12 MB) src ids bucketed by dest
//   x8    : N_NODES*32 uints        (5.12 MB) fp8 e4m3 copy of x
//   plist : NXCD*PLCAP uints        (2.69 MB) compacted per-partition edges,
//                                   packed as (c-p*PART) | (r<<13)
//
// Edge flow: prep reads each edge ONCE, routes it via LDS to its destination
// partition's compacted list (coalesced flush). bucket blocks then scatter
// with EVERY lane active, and writes to a node's bucket all come from one
// XCD (p = b&7 under round-robin dispatch) so L2 coalesces the 2B stores.
// Partition math is exact -- XCD mapping is a locality heuristic only.
//
// GEMM (fused gather): per 64-node block, stage bf16(x) self-half to LDS,
// gather fp8 neighbor rows directly into the LDS agg-half (fp32 accumulate,
// mean, bf16), then out = [bf16(x)|agg] @ Wcat^T + bias via 16x16x32 MFMA.
// ---------------------------------------------------------------------------

__device__ inline unsigned short f2bf(float f) {
  union { float f; unsigned int u; } v{f};
  unsigned int r = (v.u + 0x7FFFu + ((v.u >> 16) & 1u)) >> 16;  // RNE
  return (unsigned short)r;
}

__device__ inline void acc4(unsigned int v, float& a0, float& a1, float& a2,
                            float& a3) {
  f32x2 lo = __builtin_amdgcn_cvt_pk_f32_fp8(v, false);
  f32x2 hi = __builtin_amdgcn_cvt_pk_f32_fp8(v, true);
  a0 += lo.x; a1 += lo.y; a2 += hi.x; a3 += hi.y;
}

// Fused: x -> fp8 (x8), Wcat build, and (blocks < 625) edge compaction into
// per-partition lists.
__global__ __launch_bounds__(256) void prep_kernel(
    const float* __restrict__ x, const float* __restrict__ Ws,
    const float* __restrict__ Wn, const int* __restrict__ ei,
    unsigned short* __restrict__ Wcat, unsigned int* __restrict__ x8,
    unsigned int* __restrict__ plist, int* __restrict__ pcur) {
  int b = blockIdx.x;
  int t = threadIdx.x;
  int tid = b * 256 + t;  // 1,280,000 threads
  {  // x -> fp8, 4 elems/thread (covers 5.12M floats exactly)
    float4 v = *reinterpret_cast<const float4*>(x + (size_t)tid * 4);
    unsigned int u = __builtin_amdgcn_cvt_pk_fp8_f32(v.x, v.y, 0, false);
    u = __builtin_amdgcn_cvt_pk_fp8_f32(v.z, v.w, u, true);
    x8[tid] = u;
  }
  if (tid < 8192) {  // Wcat: 128 x 256, 4 elems/thread
    int j = tid >> 6;
    int kq = tid & 63;
    int k0 = kq * 4;
    float4 v = (kq < 32)
        ? *reinterpret_cast<const float4*>(Ws + j * D + k0)
        : *reinterpret_cast<const float4*>(Wn + j * D + (k0 - D));
    ushort4 h;
    h.x = f2bf(v.x); h.y = f2bf(v.y); h.z = f2bf(v.z); h.w = f2bf(v.w);
    *reinterpret_cast<ushort4*>(Wcat + j * KCAT + k0) = h;
  }
  __shared__ int lcnt[NXCD];
  __shared__ int lbase[NXCD];
  __shared__ unsigned int lbuf[NXCD][CCAP];
  if (b < 625) {  // compact chunk b (1024 edges) into partition lists
    if (t < NXCD) lcnt[t] = 0;
    __syncthreads();
    int q = b * 256 + t;
    int4 r = reinterpret_cast<const int4*>(ei)[q];
    int4 c = reinterpret_cast<const int4*>(ei + N_EDGES)[q];
    {
      int p = c.x / PART;
      lbuf[p][atomicAdd(&lcnt[p], 1)] =
          (unsigned)(c.x - p * PART) | ((unsigned)r.x << 13);
    }
    {
      int p = c.y / PART;
      lbuf[p][atomicAdd(&lcnt[p], 1)] =
          (unsigned)(c.y - p * PART) | ((unsigned)r.y << 13);
    }
    {
      int p = c.z / PART;
      lbuf[p][atomicAdd(&lcnt[p], 1)] =
          (unsigned)(c.z - p * PART) | ((unsigned)r.z << 13);
    }
    {
      int p = c.w / PART;
      lbuf[p][atomicAdd(&lcnt[p], 1)] =
          (unsigned)(c.w - p * PART) | ((unsigned)r.w << 13);
    }
    __syncthreads();
    if (t < NXCD) lbase[t] = atomicAdd(&pcur[t], lcnt[t]);
    __syncthreads();
#pragma unroll
    for (int p = 0; p < NXCD; ++p)
      for (int i = t; i < lcnt[p]; i += 256)
        plist[(size_t)p * PLCAP + lbase[p] + i] = lbuf[p][i];
  }
}

// Scatter compacted edges into per-dest buckets. p = b&7 keeps each
// partition's writes on one XCD; every lane processes a real edge.
__global__ __launch_bounds__(256) void bucket_kernel(
    const unsigned int* __restrict__ plist, const int* __restrict__ pcur,
    int* __restrict__ deg, unsigned short* __restrict__ slot) {
  int b = blockIdx.x;
  int t = threadIdx.x;
  int p = b & (NXCD - 1);
  int idx = b >> 3;  // [0, 313)
  int n = pcur[p];
  int chunk = (n + 312) / 313;
  int start = idx * chunk;
  int end = min(n, start + chunk);
  const unsigned int* lp = plist + (size_t)p * PLCAP;
  int base = p * PART;
  for (int i = start + t; i < end; i += 256) {
    unsigned int e = lp[i];
    int c = base + (int)(e & 0x1FFFu);
    unsigned short r = (unsigned short)(e >> 13);
    slot[(size_t)c * CAP + atomicAdd(&deg[c], 1)] = r;
  }
}

// Fused gather + bf16 MFMA GEMM:
//   out[40000][128] = [bf16(x) | mean_fp8_neighbors] @ Wcat^T + bias
// 64 nodes/block, 4 waves; wave w computes rows 0..63 x cols [w*32,w*32+32).
__global__ __launch_bounds__(256) void sage_gemm_kernel(
    const float* __restrict__ x, const unsigned int* __restrict__ x8,
    const int* __restrict__ deg, const unsigned short* __restrict__ slot,
    const unsigned short* __restrict__ Wcat, const float* __restrict__ bias,
    float* __restrict__ out) {
  __shared__ __align__(16) char Abuf[64 * 512];  // 32 KiB
  const int t = threadIdx.x;
  const int wave = t >> 6;
  const int lane = t & 63;
  const int node0 = blockIdx.x * 64;

  // B fragments (L2-hot Wcat), 64 VGPR.
  short8v breg[2][8];
#pragma unroll
  for (int jg = 0; jg < 2; ++jg) {
    int col = wave * 32 + jg * 16 + (lane & 15);
#pragma unroll
    for (int ks = 0; ks < 8; ++ks) {
      int k0 = ks * 32 + (lane >> 4) * 8;
      breg[jg][ks] =
          *reinterpret_cast<const short8v*>(Wcat + (size_t)col * KCAT + k0);
    }
  }

  // Self half (slots 0..15, swizzled): fp32 x -> bf16 inline.
#pragma unroll
  for (int i = 0; i < 4; ++i) {
    int q = i * 256 + t;  // [0, 1024)
    int row = q >> 4;
    int s = q & 15;
    const float* xp = x + (size_t)(node0 + row) * D + s * 8;
    float4 v0 = *reinterpret_cast<const float4*>(xp);
    float4 v1 = *reinterpret_cast<const float4*>(xp + 4);
    ushort4 h0, h1;
    h0.x = f2bf(v0.x); h0.y = f2bf(v0.y); h0.z = f2bf(v0.z); h0.w = f2bf(v0.w);
    h1.x = f2bf(v1.x); h1.y = f2bf(v1.y); h1.z = f2bf(v1.z); h1.w = f2bf(v1.w);
    char* dst = Abuf + row * 512 + ((s ^ (row & 7)) << 4);
    *reinterpret_cast<ushort4*>(dst) = h0;
    *reinterpret_cast<ushort4*>(dst + 8) = h1;
  }

  // Gather phase: 8 half-waves x 8 nodes, 2-node interleave (16 outstanding
  // fp8 row loads). Mean written straight into LDS agg half (slots 16..31).
  {
    int hw = t >> 5;
    int l = t & 31;
#pragma unroll
    for (int pr = 0; pr < 4; ++pr) {
      int i0 = hw * 8 + pr * 2;
      int n0 = node0 + i0;
      int nd0 = deg[n0], nd1 = deg[n0 + 1];
      const unsigned short* sp0 = slot + (size_t)n0 * CAP;
      const unsigned short* sp1 = sp0 + CAP;
      float a00 = 0.f, a01 = 0.f, a02 = 0.f, a03 = 0.f;
      float a10 = 0.f, a11 = 0.f, a12 = 0.f, a13 = 0.f;
      int m = (nd0 < nd1 ? nd0 : nd1) & ~7;
      int e = 0;
      for (; e < m; e += 8) {  // fused: 16 loads in flight
        unsigned int v0[8], v1[8];
#pragma unroll
        for (int j = 0; j < 8; ++j) v0[j] = x8[(size_t)sp0[e + j] * 32 + l];
#pragma unroll
        for (int j = 0; j < 8; ++j) v1[j] = x8[(size_t)sp1[e + j] * 32 + l];
#pragma unroll
        for (int j = 0; j < 8; ++j) acc4(v0[j], a00, a01, a02, a03);
#pragma unroll
        for (int j = 0; j < 8; ++j) acc4(v1[j], a10, a11, a12, a13);
      }
      int e0 = e;
      for (; e0 + 8 <= nd0; e0 += 8) {
        unsigned int v[8];
#pragma unroll
        for (int j = 0; j < 8; ++j) v[j] = x8[(size_t)sp0[e0 + j] * 32 + l];
#pragma unroll
        for (int j = 0; j < 8; ++j) acc4(v[j], a00, a01, a02, a03);
      }
      for (; e0 + 4 <= nd0; e0 += 4) {
        unsigned int v[4];
#pragma unroll
        for (int j = 0; j < 4; ++j) v[j] = x8[(size_t)sp0[e0 + j] * 32 + l];
#pragma unroll
        for (int j = 0; j < 4; ++j) acc4(v[j], a00, a01, a02, a03);
      }
      for (; e0 < nd0; ++e0) acc4(x8[(size_t)sp0[e0] * 32 + l], a00, a01, a02, a03);
      int e1 = e;
      for (; e1 + 8 <= nd1; e1 += 8) {
        unsigned int v[8];
#pragma unroll
        for (int j = 0; j < 8; ++j) v[j] = x8[(size_t)sp1[e1 + j] * 32 + l];
#pragma unroll
        for (int j = 0; j < 8; ++j) acc4(v[j], a10, a11, a12, a13);
      }
      for (; e1 + 4 <= nd1; e1 += 4) {
        unsigned int v[4];
#pragma unroll
        for (int j = 0; j < 4; ++j) v[j] = x8[(size_t)sp1[e1 + j] * 32 + l];
#pragma unroll
        for (int j = 0; j < 4; ++j) acc4(v[j], a10, a11, a12, a13);
      }
      for (; e1 < nd1; ++e1) acc4(x8[(size_t)sp1[e1] * 32 + l], a10, a11, a12, a13);

      // lane l holds bytes [l*8, l*8+8) of the 256B agg half.
      int s = 16 + (l >> 1);
      int off = (l & 1) << 3;
      {
        float inv = 1.0f / fmaxf((float)nd0, 1.0f);
        ushort4 h;
        h.x = f2bf(a00 * inv); h.y = f2bf(a01 * inv);
        h.z = f2bf(a02 * inv); h.w = f2bf(a03 * inv);
        int row = i0;
        *reinterpret_cast<ushort4*>(
            Abuf + row * 512 + ((s ^ (row & 7)) << 4) + off) = h;
      }
      {
        float inv = 1.0f / fmaxf((float)nd1, 1.0f);
        ushort4 h;
        h.x = f2bf(a10 * inv); h.y = f2bf(a11 * inv);
        h.z = f2bf(a12 * inv); h.w = f2bf(a13 * inv);
        int row = i0 + 1;
        *reinterpret_cast<ushort4*>(
            Abuf + row * 512 + ((s ^ (row & 7)) << 4) + off) = h;
      }
    }
  }
  __syncthreads();

  const int srow = lane & 15;
  const int c7 = lane & 7;
  const int sb = lane >> 4;

  f32x4 acc[4][2] = {};
#pragma unroll
  for (int ks = 0; ks < 8; ++ks) {
    short8v af[4];
#pragma unroll
    for (int mf = 0; mf < 4; ++mf) {
      int row = mf * 16 + srow;
      int sl = (ks * 4 + sb) ^ c7;
      af[mf] = *reinterpret_cast<const short8v*>(Abuf + row * 512 + (sl << 4));
    }
#pragma unroll
    for (int mf = 0; mf < 4; ++mf)
#pragma unroll
      for (int jg = 0; jg < 2; ++jg)
        acc[mf][jg] = __builtin_amdgcn_mfma_f32_16x16x32_bf16(
            af[mf], breg[jg][ks], acc[mf][jg], 0, 0, 0);
  }

  // D layout: col = lane&15, row = (lane>>4)*4 + reg
#pragma unroll
  for (int jg = 0; jg < 2; ++jg) {
    int col = wave * 32 + jg * 16 + (lane & 15);
    float bv = bias[col];
#pragma unroll
    for (int mf = 0; mf < 4; ++mf) {
      int rbase = node0 + mf * 16 + (lane >> 4) * 4;
#pragma unroll
      for (int r = 0; r < 4; ++r) {
        out[(size_t)(rbase + r) * D + col] = acc[mf][jg][r] + bv;
      }
    }
  }
}

extern "C" void kernel_launch(void* const* d_in, const int* in_sizes, int n_in,
                              void* d_out, int out_size, void* d_ws, size_t ws_size,
                              hipStream_t stream) {
  const float* x    = (const float*)d_in[0];
  const int*   ei   = (const int*)d_in[1];
  const float* Ws   = (const float*)d_in[2];
  const float* Wn   = (const float*)d_in[3];
  const float* bias = (const float*)d_in[4];
  float* out = (float*)d_out;

  unsigned short* Wcat = (unsigned short*)d_ws;              // 64 KB
  int* deg = (int*)(Wcat + 128 * KCAT);                      // 160 KB
  int* pcur = deg + N_NODES;                                 // 32 B
  unsigned short* slot = (unsigned short*)(pcur + NXCD);     // 5.12 MB
  unsigned int* x8 =
      (unsigned int*)(slot + (size_t)N_NODES * CAP);         // 5.12 MB
  unsigned int* plist = x8 + (size_t)N_NODES * 32;           // 2.69 MB

  hipMemsetAsync(deg, 0, (N_NODES + NXCD) * sizeof(int), stream);
  prep_kernel<<<5000, 256, 0, stream>>>(x, Ws, Wn, ei, Wcat, x8, plist, pcur);
  bucket_kernel<<<2504, 256, 0, stream>>>(plist, pcur, deg, slot);
  sage_gemm_kernel<<<625, 256, 0, stream>>>(x, x8, deg, slot, Wcat, bias, out);
}

// Round 12
// 79.388 us; speedup vs baseline: 1.3048x; 1.3048x over previous
//
#include <hip/hip_runtime.h>

#define N_NODES 40000
#define N_EDGES 640000
#define D 128
#define KCAT 256    // concat-K: [x | agg]
#define CAP 64      // bucket capacity; P(deg>=64 | Binom(640K,1/40K)) ~ 4e-13 total
#define NXCD 8
#define PART 5000   // nodes per XCD partition
#define PLCAP 84000 // per-partition compacted-list capacity (mean 80K, +15 sigma)
#define CCAP 224    // per-block per-partition compact capacity (mean 128, +9 sigma)

typedef __attribute__((ext_vector_type(8))) short short8v;
typedef __attribute__((ext_vector_type(4))) float f32x4;
typedef __attribute__((ext_vector_type(2))) float f32x2;

// ---------------------------------------------------------------------------
// Pipeline (5 dispatches):
//   memset(deg+pcur) -> prep (x->fp8 + Wcat + edge compaction)
//   -> bucket (XCD-local scatter, all lanes active)
//   -> gather (fp8 mean-aggregate, high-occupancy standalone)
//   -> gemm (pure MFMA, inline fp32->bf16 self-half)
//
// Workspace (20.7 MB):
//   Wcat    : 128*256 bf16 (64 KB)   B^T layout: Wcat[j][k], k<128->Ws else Wn
//   deg     : N_NODES ints           atomic cursors (zeroed by memset)
//   pcur    : NXCD ints              per-partition list cursors (zeroed)
//   slot    : N_NODES*CAP ushorts    (5.12 MB) src ids bucketed by dest
//   x8      : N_NODES*32 uints       (5.12 MB) fp8 e4m3 copy of x
//   scratch : 10.24 MB, time-shared:
//       plist (uints, 2.69 MB)  live prep -> bucket
//       aggb  (bf16, 10.24 MB)  live gather -> gemm
//
// Lesson from R11: gather is latency-bound and needs max TLP (5000 blocks);
// the GEMM wants a small grid. Fusing them starves the gather -> keep split.
// ---------------------------------------------------------------------------

__device__ inline unsigned short f2bf(float f) {
  union { float f; unsigned int u; } v{f};
  unsigned int r = (v.u + 0x7FFFu + ((v.u >> 16) & 1u)) >> 16;  // RNE
  return (unsigned short)r;
}

__device__ inline void acc4(unsigned int v, float& a0, float& a1, float& a2,
                            float& a3) {
  f32x2 lo = __builtin_amdgcn_cvt_pk_f32_fp8(v, false);
  f32x2 hi = __builtin_amdgcn_cvt_pk_f32_fp8(v, true);
  a0 += lo.x; a1 += lo.y; a2 += hi.x; a3 += hi.y;
}

// Fused: x -> fp8 (x8), Wcat build, and (blocks < 625) single-pass edge
// compaction into per-destination-partition lists via LDS.
__global__ __launch_bounds__(256) void prep_kernel(
    const float* __restrict__ x, const float* __restrict__ Ws,
    const float* __restrict__ Wn, const int* __restrict__ ei,
    unsigned short* __restrict__ Wcat, unsigned int* __restrict__ x8,
    unsigned int* __restrict__ plist, int* __restrict__ pcur) {
  int b = blockIdx.x;
  int t = threadIdx.x;
  int tid = b * 256 + t;  // 1,280,000 threads
  {  // x -> fp8, 4 elems/thread (covers 5.12M floats exactly)
    float4 v = *reinterpret_cast<const float4*>(x + (size_t)tid * 4);
    unsigned int u = __builtin_amdgcn_cvt_pk_fp8_f32(v.x, v.y, 0, false);
    u = __builtin_amdgcn_cvt_pk_fp8_f32(v.z, v.w, u, true);
    x8[tid] = u;
  }
  if (tid < 8192) {  // Wcat: 128 x 256, 4 elems/thread
    int j = tid >> 6;
    int kq = tid & 63;
    int k0 = kq * 4;
    float4 v = (kq < 32)
        ? *reinterpret_cast<const float4*>(Ws + j * D + k0)
        : *reinterpret_cast<const float4*>(Wn + j * D + (k0 - D));
    ushort4 h;
    h.x = f2bf(v.x); h.y = f2bf(v.y); h.z = f2bf(v.z); h.w = f2bf(v.w);
    *reinterpret_cast<ushort4*>(Wcat + j * KCAT + k0) = h;
  }
  __shared__ int lcnt[NXCD];
  __shared__ int lbase[NXCD];
  __shared__ unsigned int lbuf[NXCD][CCAP];
  if (b < 625) {  // compact chunk b (1024 edges) into partition lists
    if (t < NXCD) lcnt[t] = 0;
    __syncthreads();
    int q = b * 256 + t;
    int4 r = reinterpret_cast<const int4*>(ei)[q];
    int4 c = reinterpret_cast<const int4*>(ei + N_EDGES)[q];
    {
      int p = c.x / PART;
      lbuf[p][atomicAdd(&lcnt[p], 1)] =
          (unsigned)(c.x - p * PART) | ((unsigned)r.x << 13);
    }
    {
      int p = c.y / PART;
      lbuf[p][atomicAdd(&lcnt[p], 1)] =
          (unsigned)(c.y - p * PART) | ((unsigned)r.y << 13);
    }
    {
      int p = c.z / PART;
      lbuf[p][atomicAdd(&lcnt[p], 1)] =
          (unsigned)(c.z - p * PART) | ((unsigned)r.z << 13);
    }
    {
      int p = c.w / PART;
      lbuf[p][atomicAdd(&lcnt[p], 1)] =
          (unsigned)(c.w - p * PART) | ((unsigned)r.w << 13);
    }
    __syncthreads();
    if (t < NXCD) lbase[t] = atomicAdd(&pcur[t], lcnt[t]);
    __syncthreads();
#pragma unroll
    for (int p = 0; p < NXCD; ++p)
      for (int i = t; i < lcnt[p]; i += 256)
        plist[(size_t)p * PLCAP + lbase[p] + i] = lbuf[p][i];
  }
}

// Scatter compacted edges into per-dest buckets. p = b&7 keeps each
// partition's writes on one XCD's L2; every lane processes a real edge.
__global__ __launch_bounds__(256) void bucket_kernel(
    const unsigned int* __restrict__ plist, const int* __restrict__ pcur,
    int* __restrict__ deg, unsigned short* __restrict__ slot) {
  int b = blockIdx.x;
  int t = threadIdx.x;
  int p = b & (NXCD - 1);
  int idx = b >> 3;  // [0, 313)
  int n = pcur[p];
  int chunk = (n + 312) / 313;
  int start = idx * chunk;
  int end = min(n, start + chunk);
  const unsigned int* lp = plist + (size_t)p * PLCAP;
  int base = p * PART;
  for (int i = start + t; i < end; i += 256) {
    unsigned int e = lp[i];
    int c = base + (int)(e & 0x1FFFu);
    unsigned short r = (unsigned short)(e >> 13);
    slot[(size_t)c * CAP + atomicAdd(&deg[c], 1)] = r;
  }
}

// Mean-aggregate fp8 neighbor rows (128 B/edge); fp32 accumulate; bf16 out.
// Half-wave per node (32 lanes x 1 uint = 4 fp8), 8-deep unroll for MLP.
// Standalone & LDS-free: 5000 blocks -> high occupancy hides gather latency.
__global__ __launch_bounds__(256) void gather_kernel(
    const unsigned int* __restrict__ x8, unsigned short* __restrict__ aggb,
    const int* __restrict__ deg, const unsigned short* __restrict__ slot) {
  int node = blockIdx.x * 8 + (threadIdx.x >> 5);
  int l = threadIdx.x & 31;
  int nd = deg[node];
  const unsigned short* sp = slot + (size_t)node * CAP;
  float a0 = 0.f, a1 = 0.f, a2 = 0.f, a3 = 0.f;
  int e = 0;
  for (; e + 8 <= nd; e += 8) {
    unsigned int v[8];
#pragma unroll
    for (int j = 0; j < 8; ++j) v[j] = x8[(size_t)sp[e + j] * 32 + l];
#pragma unroll
    for (int j = 0; j < 8; ++j) acc4(v[j], a0, a1, a2, a3);
  }
  for (; e + 4 <= nd; e += 4) {
    unsigned int v[4];
#pragma unroll
    for (int j = 0; j < 4; ++j) v[j] = x8[(size_t)sp[e + j] * 32 + l];
#pragma unroll
    for (int j = 0; j < 4; ++j) acc4(v[j], a0, a1, a2, a3);
  }
  for (; e < nd; ++e) acc4(x8[(size_t)sp[e] * 32 + l], a0, a1, a2, a3);
  float inv = 1.0f / fmaxf((float)nd, 1.0f);
  ushort4 h;
  h.x = f2bf(a0 * inv); h.y = f2bf(a1 * inv);
  h.z = f2bf(a2 * inv); h.w = f2bf(a3 * inv);
  *reinterpret_cast<ushort4*>(aggb + (size_t)node * D + l * 4) = h;
}

// bf16 MFMA GEMM: out[40000][128] = [bf16(x)|aggb] @ Wcat^T + bias.
// 64 nodes/block, 4 waves; wave w computes rows 0..63 x cols [w*32, w*32+32).
__global__ __launch_bounds__(256) void sage_gemm_kernel(
    const float* __restrict__ x, const unsigned short* __restrict__ aggb,
    const unsigned short* __restrict__ Wcat, const float* __restrict__ bias,
    float* __restrict__ out) {
  __shared__ __align__(16) char Abuf[64 * 512];  // 32 KiB
  const int t = threadIdx.x;
  const int wave = t >> 6;
  const int lane = t & 63;
  const int node0 = blockIdx.x * 64;

  short8v breg[2][8];
#pragma unroll
  for (int jg = 0; jg < 2; ++jg) {
    int col = wave * 32 + jg * 16 + (lane & 15);
#pragma unroll
    for (int ks = 0; ks < 8; ++ks) {
      int k0 = ks * 32 + (lane >> 4) * 8;
      breg[jg][ks] =
          *reinterpret_cast<const short8v*>(Wcat + (size_t)col * KCAT + k0);
    }
  }

  // Stage A-tile into LDS with slot ^= (row&7) swizzle.
  // Self half (slots 0..15): fp32 x -> bf16 inline.
#pragma unroll
  for (int i = 0; i < 4; ++i) {
    int q = i * 256 + t;  // [0, 1024)
    int row = q >> 4;
    int s = q & 15;
    const float* xp = x + (size_t)(node0 + row) * D + s * 8;
    float4 v0 = *reinterpret_cast<const float4*>(xp);
    float4 v1 = *reinterpret_cast<const float4*>(xp + 4);
    ushort4 h0, h1;
    h0.x = f2bf(v0.x); h0.y = f2bf(v0.y); h0.z = f2bf(v0.z); h0.w = f2bf(v0.w);
    h1.x = f2bf(v1.x); h1.y = f2bf(v1.y); h1.z = f2bf(v1.z); h1.w = f2bf(v1.w);
    char* dst = Abuf + row * 512 + ((s ^ (row & 7)) << 4);
    *reinterpret_cast<ushort4*>(dst) = h0;
    *reinterpret_cast<ushort4*>(dst + 8) = h1;
  }
  // Agg half (slots 16..31): bf16 copy.
#pragma unroll
  for (int i = 0; i < 4; ++i) {
    int q = i * 256 + t;  // [0, 1024)
    int row = q >> 4;
    int s = 16 + (q & 15);
    int4 v = *reinterpret_cast<const int4*>(aggb + (size_t)(node0 + row) * D +
                                            (q & 15) * 8);
    *reinterpret_cast<int4*>(Abuf + row * 512 + ((s ^ (row & 7)) << 4)) = v;
  }
  __syncthreads();

  const int srow = lane & 15;
  const int c7 = lane & 7;
  const int sb = lane >> 4;

  f32x4 acc[4][2] = {};
#pragma unroll
  for (int ks = 0; ks < 8; ++ks) {
    short8v af[4];
#pragma unroll
    for (int mf = 0; mf < 4; ++mf) {
      int row = mf * 16 + srow;
      int sl = (ks * 4 + sb) ^ c7;
      af[mf] = *reinterpret_cast<const short8v*>(Abuf + row * 512 + (sl << 4));
    }
#pragma unroll
    for (int mf = 0; mf < 4; ++mf)
#pragma unroll
      for (int jg = 0; jg < 2; ++jg)
        acc[mf][jg] = __builtin_amdgcn_mfma_f32_16x16x32_bf16(
            af[mf], breg[jg][ks], acc[mf][jg], 0, 0, 0);
  }

  // D layout: col = lane&15, row = (lane>>4)*4 + reg
#pragma unroll
  for (int jg = 0; jg < 2; ++jg) {
    int col = wave * 32 + jg * 16 + (lane & 15);
    float bv = bias[col];
#pragma unroll
    for (int mf = 0; mf < 4; ++mf) {
      int rbase = node0 + mf * 16 + (lane >> 4) * 4;
#pragma unroll
      for (int r = 0; r < 4; ++r) {
        out[(size_t)(rbase + r) * D + col] = acc[mf][jg][r] + bv;
      }
    }
  }
}

extern "C" void kernel_launch(void* const* d_in, const int* in_sizes, int n_in,
                              void* d_out, int out_size, void* d_ws, size_t ws_size,
                              hipStream_t stream) {
  const float* x    = (const float*)d_in[0];
  const int*   ei   = (const int*)d_in[1];
  const float* Ws   = (const float*)d_in[2];
  const float* Wn   = (const float*)d_in[3];
  const float* bias = (const float*)d_in[4];
  float* out = (float*)d_out;

  unsigned short* Wcat = (unsigned short*)d_ws;              // 64 KB
  int* deg = (int*)(Wcat + 128 * KCAT);                      // 160 KB
  int* pcur = deg + N_NODES;                                 // 32 B
  unsigned short* slot = (unsigned short*)(pcur + NXCD);     // 5.12 MB
  unsigned int* x8 =
      (unsigned int*)(slot + (size_t)N_NODES * CAP);         // 5.12 MB
  // scratch region, time-shared: plist (prep->bucket), aggb (gather->gemm)
  void* scratch = (void*)(x8 + (size_t)N_NODES * 32);        // 10.24 MB
  unsigned int* plist = (unsigned int*)scratch;
  unsigned short* aggb = (unsigned short*)scratch;

  hipMemsetAsync(deg, 0, (N_NODES + NXCD) * sizeof(int), stream);
  prep_kernel<<<5000, 256, 0, stream>>>(x, Ws, Wn, ei, Wcat, x8, plist, pcur);
  bucket_kernel<<<2504, 256, 0, stream>>>(plist, pcur, deg, slot);
  gather_kernel<<<5000, 256, 0, stream>>>(x8, aggb, deg, slot);
  sage_gemm_kernel<<<625, 256, 0, stream>>>(x, aggb, Wcat, bias, out);
}

// Round 13
// 72.233 us; speedup vs baseline: 1.4340x; 1.0991x over previous
//
#include <hip/hip_runtime.h>

#define N_NODES 40000
#define N_EDGES 640000
#define D 128
#define KCAT 256   // concat-K: [x | agg]
#define CAP 64     // bucket capacity; P(deg>=64 | Binom(640K,1/40K)) ~ 4e-13 total
#define NXCD 8
#define PART 5000  // nodes per XCD partition

typedef __attribute__((ext_vector_type(8))) short short8v;
typedef __attribute__((ext_vector_type(4))) float f32x4;
typedef __attribute__((ext_vector_type(2))) float f32x2;

// ---------------------------------------------------------------------------
// Pipeline (3 dispatches):
//   memset(deg) -> prep (x->fp8 + Wcat + XCD-local direct bucketing)
//               -> fused gather+gemm (32-node tiles, 1250 blocks)
//
// Workspace (~10.5 MB):
//   Wcat : 128*256 bf16 (64 KB)   B^T layout: Wcat[j][k], k<128->Ws else Wn
//   deg  : N_NODES ints           atomic cursors (zeroed by memset)
//   slot : N_NODES*CAP ushorts    (5.12 MB) src ids bucketed by dest
//   x8   : N_NODES*32 uints       (5.12 MB) fp8 e4m3 copy of x
//
// R11 lesson: fused gather died at 625 blocks (2.4/CU, 12% occupancy).
// This round: 32-node tiles -> 1250 blocks, 16 KB LDS, B loaded per-k-step
// (not 64 resident VGPRs) -> ~5 blocks/CU, ~20 waves/CU for the gather phase.
// R12 lesson: the 640K deg-atomics must overlap prep's streaming work, not
// sit in their own dispatch -> direct bucketing stays fused in prep.
// ---------------------------------------------------------------------------

__device__ inline unsigned short f2bf(float f) {
  union { float f; unsigned int u; } v{f};
  unsigned int r = (v.u + 0x7FFFu + ((v.u >> 16) & 1u)) >> 16;  // RNE
  return (unsigned short)r;
}

__device__ inline void acc4(unsigned int v, float& a0, float& a1, float& a2,
                            float& a3) {
  f32x2 lo = __builtin_amdgcn_cvt_pk_f32_fp8(v, false);
  f32x2 hi = __builtin_amdgcn_cvt_pk_f32_fp8(v, true);
  a0 += lo.x; a1 += lo.y; a2 += hi.x; a3 += hi.y;
}

// Fused: x -> fp8 (x8), Wcat build, balanced XCD-local direct bucketing.
// Block b handles destination partition p=b&7 over edge chunk b>>3.
__global__ __launch_bounds__(256) void prep_kernel(
    const float* __restrict__ x, const float* __restrict__ Ws,
    const float* __restrict__ Wn, const int* __restrict__ ei,
    unsigned short* __restrict__ Wcat, unsigned int* __restrict__ x8,
    int* __restrict__ deg, unsigned short* __restrict__ slot) {
  int b = blockIdx.x;
  int t = threadIdx.x;
  int tid = b * 256 + t;  // 1,280,000 threads
  {  // x -> fp8, 4 elems/thread (covers 5.12M floats exactly)
    float4 v = *reinterpret_cast<const float4*>(x + (size_t)tid * 4);
    unsigned int u = __builtin_amdgcn_cvt_pk_fp8_f32(v.x, v.y, 0, false);
    u = __builtin_amdgcn_cvt_pk_fp8_f32(v.z, v.w, u, true);
    x8[tid] = u;
  }
  if (tid < 8192) {  // Wcat: 128 x 256, 4 elems/thread
    int j = tid >> 6;
    int kq = tid & 63;
    int k0 = kq * 4;
    float4 v = (kq < 32)
        ? *reinterpret_cast<const float4*>(Ws + j * D + k0)
        : *reinterpret_cast<const float4*>(Wn + j * D + (k0 - D));
    ushort4 h;
    h.x = f2bf(v.x); h.y = f2bf(v.y); h.z = f2bf(v.z); h.w = f2bf(v.w);
    *reinterpret_cast<ushort4*>(Wcat + j * KCAT + k0) = h;
  }
  {  // balanced XCD-partitioned bucketing: 1 int4 (4 edges) per thread
    int p = b & (NXCD - 1);
    int chunk = b >> 3;  // [0, 625)
    int lo = p * PART;
    int q = chunk * 256 + t;
    int4 r = reinterpret_cast<const int4*>(ei)[q];
    int4 c = reinterpret_cast<const int4*>(ei + N_EDGES)[q];
    if ((unsigned)(c.x - lo) < PART)
      slot[(size_t)c.x * CAP + atomicAdd(&deg[c.x], 1)] = (unsigned short)r.x;
    if ((unsigned)(c.y - lo) < PART)
      slot[(size_t)c.y * CAP + atomicAdd(&deg[c.y], 1)] = (unsigned short)r.y;
    if ((unsigned)(c.z - lo) < PART)
      slot[(size_t)c.z * CAP + atomicAdd(&deg[c.z], 1)] = (unsigned short)r.z;
    if ((unsigned)(c.w - lo) < PART)
      slot[(size_t)c.w * CAP + atomicAdd(&deg[c.w], 1)] = (unsigned short)r.w;
  }
}

// Fused gather + bf16 MFMA GEMM, 32 nodes/block (1250 blocks):
//   out[40000][128] = [bf16(x) | mean_fp8_neighbors] @ Wcat^T + bias
// 4 waves; wave w computes rows 0..31 x cols [w*32, w*32+32).
__global__ __launch_bounds__(256) void sage_gemm_kernel(
    const float* __restrict__ x, const unsigned int* __restrict__ x8,
    const int* __restrict__ deg, const unsigned short* __restrict__ slot,
    const unsigned short* __restrict__ Wcat, const float* __restrict__ bias,
    float* __restrict__ out) {
  __shared__ __align__(16) char Abuf[32 * 512];  // 16 KiB
  const int t = threadIdx.x;
  const int wave = t >> 6;
  const int lane = t & 63;
  const int node0 = blockIdx.x * 32;

  // Self half (slots 0..15, swizzled): fp32 x -> bf16 inline. 512 jobs.
#pragma unroll
  for (int i = 0; i < 2; ++i) {
    int q = i * 256 + t;  // [0, 512)
    int row = q >> 4;
    int s = q & 15;
    const float* xp = x + (size_t)(node0 + row) * D + s * 8;
    float4 v0 = *reinterpret_cast<const float4*>(xp);
    float4 v1 = *reinterpret_cast<const float4*>(xp + 4);
    ushort4 h0, h1;
    h0.x = f2bf(v0.x); h0.y = f2bf(v0.y); h0.z = f2bf(v0.z); h0.w = f2bf(v0.w);
    h1.x = f2bf(v1.x); h1.y = f2bf(v1.y); h1.z = f2bf(v1.z); h1.w = f2bf(v1.w);
    char* dst = Abuf + row * 512 + ((s ^ (row & 7)) << 4);
    *reinterpret_cast<ushort4*>(dst) = h0;
    *reinterpret_cast<ushort4*>(dst + 8) = h1;
  }

  // Gather phase: 8 half-waves x 4 nodes each, 8-deep MLP unroll.
  // Mean written straight into the swizzled LDS agg half (slots 16..31).
  {
    int hw = t >> 5;
    int l = t & 31;
#pragma unroll
    for (int pr = 0; pr < 4; ++pr) {
      int row = hw * 4 + pr;
      int node = node0 + row;
      int nd = deg[node];
      const unsigned short* sp = slot + (size_t)node * CAP;
      float a0 = 0.f, a1 = 0.f, a2 = 0.f, a3 = 0.f;
      int e = 0;
      for (; e + 8 <= nd; e += 8) {
        unsigned int v[8];
#pragma unroll
        for (int j = 0; j < 8; ++j) v[j] = x8[(size_t)sp[e + j] * 32 + l];
#pragma unroll
        for (int j = 0; j < 8; ++j) acc4(v[j], a0, a1, a2, a3);
      }
      for (; e + 4 <= nd; e += 4) {
        unsigned int v[4];
#pragma unroll
        for (int j = 0; j < 4; ++j) v[j] = x8[(size_t)sp[e + j] * 32 + l];
#pragma unroll
        for (int j = 0; j < 4; ++j) acc4(v[j], a0, a1, a2, a3);
      }
      for (; e < nd; ++e) acc4(x8[(size_t)sp[e] * 32 + l], a0, a1, a2, a3);
      float inv = 1.0f / fmaxf((float)nd, 1.0f);
      ushort4 h;
      h.x = f2bf(a0 * inv); h.y = f2bf(a1 * inv);
      h.z = f2bf(a2 * inv); h.w = f2bf(a3 * inv);
      int s = 16 + (l >> 1);
      int off = (l & 1) << 3;
      *reinterpret_cast<ushort4*>(
          Abuf + row * 512 + ((s ^ (row & 7)) << 4) + off) = h;
    }
  }
  __syncthreads();

  const int srow = lane & 15;
  const int c7 = lane & 7;
  const int sb = lane >> 4;

  // MFMA: 2 row-frags x 2 col-frags x 8 k-steps; B loaded per-k-step
  // from L2-hot Wcat (keeps VGPR low for gather-phase occupancy).
  f32x4 acc[2][2] = {};
#pragma unroll
  for (int ks = 0; ks < 8; ++ks) {
    short8v af[2];
#pragma unroll
    for (int mf = 0; mf < 2; ++mf) {
      int row = mf * 16 + srow;
      int sl = (ks * 4 + sb) ^ c7;
      af[mf] = *reinterpret_cast<const short8v*>(Abuf + row * 512 + (sl << 4));
    }
    short8v bf[2];
#pragma unroll
    for (int jg = 0; jg < 2; ++jg) {
      int col = wave * 32 + jg * 16 + (lane & 15);
      bf[jg] = *reinterpret_cast<const short8v*>(Wcat + (size_t)col * KCAT +
                                                 ks * 32 + sb * 8);
    }
#pragma unroll
    for (int mf = 0; mf < 2; ++mf)
#pragma unroll
      for (int jg = 0; jg < 2; ++jg)
        acc[mf][jg] = __builtin_amdgcn_mfma_f32_16x16x32_bf16(
            af[mf], bf[jg], acc[mf][jg], 0, 0, 0);
  }

  // D layout: col = lane&15, row = (lane>>4)*4 + reg
#pragma unroll
  for (int jg = 0; jg < 2; ++jg) {
    int col = wave * 32 + jg * 16 + (lane & 15);
    float bv = bias[col];
#pragma unroll
    for (int mf = 0; mf < 2; ++mf) {
      int rbase = node0 + mf * 16 + (lane >> 4) * 4;
#pragma unroll
      for (int r = 0; r < 4; ++r) {
        out[(size_t)(rbase + r) * D + col] = acc[mf][jg][r] + bv;
      }
    }
  }
}

extern "C" void kernel_launch(void* const* d_in, const int* in_sizes, int n_in,
                              void* d_out, int out_size, void* d_ws, size_t ws_size,
                              hipStream_t stream) {
  const float* x    = (const float*)d_in[0];
  const int*   ei   = (const int*)d_in[1];
  const float* Ws   = (const float*)d_in[2];
  const float* Wn   = (const float*)d_in[3];
  const float* bias = (const float*)d_in[4];
  float* out = (float*)d_out;

  unsigned short* Wcat = (unsigned short*)d_ws;              // 64 KB
  int* deg = (int*)(Wcat + 128 * KCAT);                      // 160 KB
  unsigned short* slot = (unsigned short*)(deg + N_NODES);   // 5.12 MB
  unsigned int* x8 =
      (unsigned int*)(slot + (size_t)N_NODES * CAP);         // 5.12 MB

  hipMemsetAsync(deg, 0, N_NODES * sizeof(int), stream);
  prep_kernel<<<5000, 256, 0, stream>>>(x, Ws, Wn, ei, Wcat, x8, deg, slot);
  sage_gemm_kernel<<<1250, 256, 0, stream>>>(x, x8, deg, slot, Wcat, bias,
                                             out);
}

// Round 14
// 71.753 us; speedup vs baseline: 1.4436x; 1.0067x over previous
//
#include <hip/hip_runtime.h>

#define N_NODES 40000
#define N_EDGES 640000
#define D 128
#define KCAT 256   // concat-K: [x | agg]
#define CAP 64     // bucket capacity; P(deg>=64 | Binom(640K,1/40K)) ~ 4e-13 total
#define NXCD 8
#define PART 5000  // nodes per XCD partition
#define CCAP 256   // per-block compacted-edge capacity (mean 128, +12 sigma)

typedef __attribute__((ext_vector_type(8))) short short8v;
typedef __attribute__((ext_vector_type(4))) float f32x4;
typedef __attribute__((ext_vector_type(2))) float f32x2;

// ---------------------------------------------------------------------------
// Pipeline (3 dispatches):
//   memset(deg) -> prep (x->fp8 + Wcat + LDS-compacted XCD-local bucketing)
//               -> fused gather+gemm (32-node tiles, 1250 blocks)
//
// Workspace (~10.5 MB):
//   Wcat : 128*256 bf16 (64 KB)   B^T layout: Wcat[j][k], k<128->Ws else Wn
//   deg  : N_NODES ints           atomic cursors (zeroed by memset)
//   slot : N_NODES*CAP ushorts    (5.12 MB) src ids bucketed by dest
//   x8   : N_NODES*32 uints       (5.12 MB) fp8 e4m3 copy of x
//
// Scatter (R14 change): block b = (chunk b>>3, partition p=b&7). The 4
// filter rounds now compact into LDS (cheap LDS atomics); the global
// atomic+store scatter then runs ONCE, dense, full-lane -- 1 serialized
// L2-latency chain per thread instead of 4 exec-masked sparse ones.
// Writes to a node's bucket still come from one XCD (p=b&7 under
// round-robin dispatch) so L2 coalesces the 2B stores. Partition math is
// exact; the XCD mapping is a locality heuristic only.
// ---------------------------------------------------------------------------

__device__ inline unsigned short f2bf(float f) {
  union { float f; unsigned int u; } v{f};
  unsigned int r = (v.u + 0x7FFFu + ((v.u >> 16) & 1u)) >> 16;  // RNE
  return (unsigned short)r;
}

__device__ inline void acc4(unsigned int v, float& a0, float& a1, float& a2,
                            float& a3) {
  f32x2 lo = __builtin_amdgcn_cvt_pk_f32_fp8(v, false);
  f32x2 hi = __builtin_amdgcn_cvt_pk_f32_fp8(v, true);
  a0 += lo.x; a1 += lo.y; a2 += hi.x; a3 += hi.y;
}

// Fused: x -> fp8 (x8), Wcat build, LDS-compacted XCD-local bucketing.
__global__ __launch_bounds__(256) void prep_kernel(
    const float* __restrict__ x, const float* __restrict__ Ws,
    const float* __restrict__ Wn, const int* __restrict__ ei,
    unsigned short* __restrict__ Wcat, unsigned int* __restrict__ x8,
    int* __restrict__ deg, unsigned short* __restrict__ slot) {
  int b = blockIdx.x;
  int t = threadIdx.x;
  int tid = b * 256 + t;  // 1,280,000 threads
  {  // x -> fp8, 4 elems/thread (covers 5.12M floats exactly)
    float4 v = *reinterpret_cast<const float4*>(x + (size_t)tid * 4);
    unsigned int u = __builtin_amdgcn_cvt_pk_fp8_f32(v.x, v.y, 0, false);
    u = __builtin_amdgcn_cvt_pk_fp8_f32(v.z, v.w, u, true);
    x8[tid] = u;
  }
  if (tid < 8192) {  // Wcat: 128 x 256, 4 elems/thread
    int j = tid >> 6;
    int kq = tid & 63;
    int k0 = kq * 4;
    float4 v = (kq < 32)
        ? *reinterpret_cast<const float4*>(Ws + j * D + k0)
        : *reinterpret_cast<const float4*>(Wn + j * D + (k0 - D));
    ushort4 h;
    h.x = f2bf(v.x); h.y = f2bf(v.y); h.z = f2bf(v.z); h.w = f2bf(v.w);
    *reinterpret_cast<ushort4*>(Wcat + j * KCAT + k0) = h;
  }
  // LDS-compacted XCD-partitioned bucketing.
  __shared__ int lcnt;
  __shared__ unsigned int lbuf[CCAP];
  if (t == 0) lcnt = 0;
  __syncthreads();
  int p = b & (NXCD - 1);
  int chunk = b >> 3;  // [0, 625)
  int lo = p * PART;
  int q = chunk * 256 + t;
  int4 r = reinterpret_cast<const int4*>(ei)[q];
  int4 c = reinterpret_cast<const int4*>(ei + N_EDGES)[q];
  if ((unsigned)(c.x - lo) < PART)
    lbuf[atomicAdd(&lcnt, 1)] = (unsigned)(c.x - lo) | ((unsigned)r.x << 13);
  if ((unsigned)(c.y - lo) < PART)
    lbuf[atomicAdd(&lcnt, 1)] = (unsigned)(c.y - lo) | ((unsigned)r.y << 13);
  if ((unsigned)(c.z - lo) < PART)
    lbuf[atomicAdd(&lcnt, 1)] = (unsigned)(c.z - lo) | ((unsigned)r.z << 13);
  if ((unsigned)(c.w - lo) < PART)
    lbuf[atomicAdd(&lcnt, 1)] = (unsigned)(c.w - lo) | ((unsigned)r.w << 13);
  __syncthreads();
  int n = lcnt;
  for (int i = t; i < n; i += 256) {  // dense, single latency chain
    unsigned int e = lbuf[i];
    int cdst = lo + (int)(e & 0x1FFFu);
    slot[(size_t)cdst * CAP + atomicAdd(&deg[cdst], 1)] =
        (unsigned short)(e >> 13);
  }
}

// Fused gather + bf16 MFMA GEMM, 32 nodes/block (1250 blocks):
//   out[40000][128] = [bf16(x) | mean_fp8_neighbors] @ Wcat^T + bias
// 4 waves; wave w computes rows 0..31 x cols [w*32, w*32+32).
__global__ __launch_bounds__(256) void sage_gemm_kernel(
    const float* __restrict__ x, const unsigned int* __restrict__ x8,
    const int* __restrict__ deg, const unsigned short* __restrict__ slot,
    const unsigned short* __restrict__ Wcat, const float* __restrict__ bias,
    float* __restrict__ out) {
  __shared__ __align__(16) char Abuf[32 * 512];  // 16 KiB
  const int t = threadIdx.x;
  const int wave = t >> 6;
  const int lane = t & 63;
  const int node0 = blockIdx.x * 32;

  // Self half (slots 0..15, swizzled): fp32 x -> bf16 inline. 512 jobs.
#pragma unroll
  for (int i = 0; i < 2; ++i) {
    int q = i * 256 + t;  // [0, 512)
    int row = q >> 4;
    int s = q & 15;
    const float* xp = x + (size_t)(node0 + row) * D + s * 8;
    float4 v0 = *reinterpret_cast<const float4*>(xp);
    float4 v1 = *reinterpret_cast<const float4*>(xp + 4);
    ushort4 h0, h1;
    h0.x = f2bf(v0.x); h0.y = f2bf(v0.y); h0.z = f2bf(v0.z); h0.w = f2bf(v0.w);
    h1.x = f2bf(v1.x); h1.y = f2bf(v1.y); h1.z = f2bf(v1.z); h1.w = f2bf(v1.w);
    char* dst = Abuf + row * 512 + ((s ^ (row & 7)) << 4);
    *reinterpret_cast<ushort4*>(dst) = h0;
    *reinterpret_cast<ushort4*>(dst + 8) = h1;
  }

  // Gather phase: 8 half-waves x 4 nodes each, 8-deep MLP unroll.
  // Mean written straight into the swizzled LDS agg half (slots 16..31).
  {
    int hw = t >> 5;
    int l = t & 31;
#pragma unroll
    for (int pr = 0; pr < 4; ++pr) {
      int row = hw * 4 + pr;
      int node = node0 + row;
      int nd = deg[node];
      const unsigned short* sp = slot + (size_t)node * CAP;
      float a0 = 0.f, a1 = 0.f, a2 = 0.f, a3 = 0.f;
      int e = 0;
      for (; e + 8 <= nd; e += 8) {
        unsigned int v[8];
#pragma unroll
        for (int j = 0; j < 8; ++j) v[j] = x8[(size_t)sp[e + j] * 32 + l];
#pragma unroll
        for (int j = 0; j < 8; ++j) acc4(v[j], a0, a1, a2, a3);
      }
      for (; e + 4 <= nd; e += 4) {
        unsigned int v[4];
#pragma unroll
        for (int j = 0; j < 4; ++j) v[j] = x8[(size_t)sp[e + j] * 32 + l];
#pragma unroll
        for (int j = 0; j < 4; ++j) acc4(v[j], a0, a1, a2, a3);
      }
      for (; e < nd; ++e) acc4(x8[(size_t)sp[e] * 32 + l], a0, a1, a2, a3);
      float inv = 1.0f / fmaxf((float)nd, 1.0f);
      ushort4 h;
      h.x = f2bf(a0 * inv); h.y = f2bf(a1 * inv);
      h.z = f2bf(a2 * inv); h.w = f2bf(a3 * inv);
      int s = 16 + (l >> 1);
      int off = (l & 1) << 3;
      *reinterpret_cast<ushort4*>(
          Abuf + row * 512 + ((s ^ (row & 7)) << 4) + off) = h;
    }
  }
  __syncthreads();

  const int srow = lane & 15;
  const int c7 = lane & 7;
  const int sb = lane >> 4;

  // MFMA: 2 row-frags x 2 col-frags x 8 k-steps; B loaded per-k-step
  // from L2-hot Wcat (keeps VGPR low for gather-phase occupancy).
  f32x4 acc[2][2] = {};
#pragma unroll
  for (int ks = 0; ks < 8; ++ks) {
    short8v af[2];
#pragma unroll
    for (int mf = 0; mf < 2; ++mf) {
      int row = mf * 16 + srow;
      int sl = (ks * 4 + sb) ^ c7;
      af[mf] = *reinterpret_cast<const short8v*>(Abuf + row * 512 + (sl << 4));
    }
    short8v bf[2];
#pragma unroll
    for (int jg = 0; jg < 2; ++jg) {
      int col = wave * 32 + jg * 16 + (lane & 15);
      bf[jg] = *reinterpret_cast<const short8v*>(Wcat + (size_t)col * KCAT +
                                                 ks * 32 + sb * 8);
    }
#pragma unroll
    for (int mf = 0; mf < 2; ++mf)
#pragma unroll
      for (int jg = 0; jg < 2; ++jg)
        acc[mf][jg] = __builtin_amdgcn_mfma_f32_16x16x32_bf16(
            af[mf], bf[jg], acc[mf][jg], 0, 0, 0);
  }

  // D layout: col = lane&15, row = (lane>>4)*4 + reg
#pragma unroll
  for (int jg = 0; jg < 2; ++jg) {
    int col = wave * 32 + jg * 16 + (lane & 15);
    float bv = bias[col];
#pragma unroll
    for (int mf = 0; mf < 2; ++mf) {
      int rbase = node0 + mf * 16 + (lane >> 4) * 4;
#pragma unroll
      for (int r = 0; r < 4; ++r) {
        out[(size_t)(rbase + r) * D + col] = acc[mf][jg][r] + bv;
      }
    }
  }
}

extern "C" void kernel_launch(void* const* d_in, const int* in_sizes, int n_in,
                              void* d_out, int out_size, void* d_ws, size_t ws_size,
                              hipStream_t stream) {
  const float* x    = (const float*)d_in[0];
  const int*   ei   = (const int*)d_in[1];
  const float* Ws   = (const float*)d_in[2];
  const float* Wn   = (const float*)d_in[3];
  const float* bias = (const float*)d_in[4];
  float* out = (float*)d_out;

  unsigned short* Wcat = (unsigned short*)d_ws;              // 64 KB
  int* deg = (int*)(Wcat + 128 * KCAT);                      // 160 KB
  unsigned short* slot = (unsigned short*)(deg + N_NODES);   // 5.12 MB
  unsigned int* x8 =
      (unsigned int*)(slot + (size_t)N_NODES * CAP);         // 5.12 MB

  hipMemsetAsync(deg, 0, N_NODES * sizeof(int), stream);
  prep_kernel<<<5000, 256, 0, stream>>>(x, Ws, Wn, ei, Wcat, x8, deg, slot);
  sage_gemm_kernel<<<1250, 256, 0, stream>>>(x, x8, deg, slot, Wcat, bias,
                                             out);
}